// Round 8
// baseline (282.440 us; speedup 1.0000x reference)
//
#include <hip/hip_runtime.h>
#include <hip/hip_bf16.h>

#define TD 49
#define BD 16
#define ND 64
#define HD 128

typedef float  f32x4  __attribute__((ext_vector_type(4)));
typedef __bf16 bf16x8 __attribute__((ext_vector_type(8)));
typedef __bf16 bf16x4 __attribute__((ext_vector_type(4)));

// ---------------- workspace layout (bf16 element offsets) ----------------
#define WP_OFF   0u
#define HB_OFF   38535168u           // h  bf16 [B,T,N,H]
#define ACT_ELEMS 6422528u
#define PB_OFF   44957696u           // p  bf16
#define GB_OFF   51380224u           // g_t bf16 [B,T,H]
#define GT_ELEMS 100352u
#define ZP_OFF   51480576u           // 2048 bf16 zeros (pad source page)

#define OUT_H    0
#define OUT_CH   6422528
#define OUT_G    12845056
#define OUT_CG   12945408

#define KPAD 136
#define LDS1_BYTES 73728             // 3 slots x (A 16KB + B 8KB) -> 2 blocks/CU
#define LDS2_BYTES 118784

__device__ __forceinline__ float sigf(float x) {
    return 1.0f / (1.0f + exp2f(-1.442695041f * x));
}
__device__ __forceinline__ float tanhf_fast(float x) {
    x = fminf(fmaxf(x, -20.f), 20.f);
    float e = exp2f(2.885390082f * x);
    return (e - 1.f) / (e + 1.f);
}
__device__ __forceinline__ void gload16(const void* g, void* l) {
    __builtin_amdgcn_global_load_lds((const __attribute__((address_space(1))) void*)g,
                                     (__attribute__((address_space(3))) void*)l, 16, 0, 0);
}

// ---------------------------------------------------------------------------
// prep_acts: cast h, p, g_t f32 -> bf16 into ws; fill zero page.
// ---------------------------------------------------------------------------
__global__ void prep_acts(const float* __restrict__ h, const float* __restrict__ p,
                          const float* __restrict__ g, __bf16* __restrict__ ws)
{
    unsigned i = blockIdx.x * 256u + threadIdx.x;
    const unsigned HU = ACT_ELEMS / 4u, GU = GT_ELEMS / 4u;
    const float* src;
    unsigned dst;
    if (i < HU)                 { src = h + (size_t)i * 4;          dst = HB_OFF + i * 4; }
    else if (i < 2u*HU)         { unsigned j = i - HU;   src = p + (size_t)j * 4; dst = PB_OFF + j * 4; }
    else if (i < 2u*HU + GU)    { unsigned j = i - 2u*HU; src = g + (size_t)j * 4; dst = GB_OFF + j * 4; }
    else if (i < 2u*HU + GU + 512u) {
        unsigned j = i - 2u*HU - GU;
        bf16x4 z = {};
        *(bf16x4*)(ws + ZP_OFF + j * 4) = z;
        return;
    } else return;
    f32x4 v = *(const f32x4*)src;
    bf16x4 w;
    w[0] = (__bf16)v[0]; w[1] = (__bf16)v[1]; w[2] = (__bf16)v[2]; w[3] = (__bf16)v[3];
    *(bf16x4*)(ws + dst) = w;
}

// ---------------------------------------------------------------------------
// prep_w: transpose+cast weights into W'[t][g][h=128][k=768] bf16.
// ---------------------------------------------------------------------------
__global__ __launch_bounds__(256) void prep_w(
    const float* __restrict__ U, const float* __restrict__ Wt,
    const float* __restrict__ Ws, const float* __restrict__ Zt,
    __bf16* __restrict__ wp)
{
    __shared__ __bf16 tile[64 * 132];
    int bid = blockIdx.x;
    int tg  = bid / 12;
    int c   = bid % 12;
    int t   = tg >> 3, g = tg & 7;
    int gt  = g * TD + t;
    int tid = threadIdx.x;
    int k0  = c * 64;

#pragma unroll
    for (int u = 0; u < 8; ++u) {
        int unit = u * 256 + tid;
        int kk = unit >> 5;
        int h4 = (unit & 31) << 2;
        int k  = k0 + kk;
        const float* src;
        if (k < 128)      src = U  + ((size_t)(gt * 128 + k)       << 7);
        else if (k < 512) src = Wt + ((size_t)(gt * 384 + (k-128)) << 7);
        else if (k < 640) src = Ws + ((size_t)(gt * 128 + (k-512)) << 7);
        else              src = Zt + ((size_t)(gt * 128 + (k-640)) << 7);
        f32x4 v = *(const f32x4*)(src + h4);
        bf16x4 w;
        w[0] = (__bf16)v[0]; w[1] = (__bf16)v[1]; w[2] = (__bf16)v[2]; w[3] = (__bf16)v[3];
        *(bf16x4*)(tile + kk * 132 + h4) = w;
    }
    __syncthreads();
#pragma unroll
    for (int u = 0; u < 2; ++u) {
        int unit = u * 256 + tid;
        int hh = unit >> 2;
        int kg = unit & 3;
        bf16x8 v0, v1;
#pragma unroll
        for (int j = 0; j < 8; ++j) v0[j] = tile[(kg * 16 + j) * 132 + hh];
#pragma unroll
        for (int j = 0; j < 8; ++j) v1[j] = tile[(kg * 16 + 8 + j) * 132 + hh];
        __bf16* dst = wp + (size_t)(tg * 128 + hh) * 768 + k0 + kg * 16;
        *(bf16x8*)dst       = v0;
        *(bf16x8*)(dst + 8) = v1;
    }
}

// ---------------------------------------------------------------------------
// Phase 1 (v3): 256x128 tile (4 waves x 64 rows x all 8 gates), BK=32,
// 24 K-tiles, 3 LDS slots, depth-2 prefetch, counted vmcnt(6) + raw barrier.
// 12 ds_read_b128 -> 32 MFMA per wave per step (0.375 reads/MFMA).
// Slot math: step ks stages tile ks+2 into slot (ks+2)%3 == (ks-1)%3, freed by
// the end-of-step-(ks-1) barrier; vmcnt(6) at step end => tile ks+1 landed.
// ---------------------------------------------------------------------------
__global__ __launch_bounds__(256, 2) void phase1_kernel(
    const __bf16* __restrict__ ws,
    const float* __restrict__ c_h, const float* __restrict__ c_g_t,
    const float* __restrict__ bias, float* __restrict__ out)
{
    extern __shared__ __bf16 smem[];   // A slots: elems [0,24576); B: [24576,36864)

    int bid = blockIdx.x;
    int swz = (bid & 7) * 196 + (bid >> 3);  // bijective, 1568 = 8*196
    int t     = swz >> 5;
    int rem   = swz & 31;
    int mtile = rem >> 3, ntile = rem & 7;

    int tid  = threadIdx.x;
    int wave = tid >> 6, lane = tid & 63;
    int lg = lane >> 4, l16 = lane & 15;

    const int n    = tid >> 2;                              // [0,64)
    const unsigned kesw = (((tid & 3) ^ ((tid >> 3) & 3)) << 3);  // swizzled 16B chunk
    const bool okT0 = (t > 0), okT1 = (t < TD - 1), okN = (n > 0);
    const unsigned zoff = ZP_OFF + kesw;
    const int tid8 = tid * 8;

    unsigned rowoff[4], goff[4], offB[2];
#pragma unroll
    for (int it = 0; it < 4; ++it) {
        unsigned bt_ = (unsigned)((mtile * 4 + it) * TD + t);
        rowoff[it] = bt_ * 8192u + (unsigned)(n << 7) + kesw;   // (bt*64+n)*128 + kesw
        goff[it]   = bt_ * 128u + kesw;
    }
#pragma unroll
    for (int it = 0; it < 2; ++it) {
        int row = it * 64 + n;              // [0,128)
        int g_ = row >> 4, hc = row & 15;
        offB[it] = WP_OFF + (unsigned)((t * 8 + g_) * 128 + ntile * 16 + hc) * 768u + kesw;
    }

    f32x4 acc[4][8];
    const f32x4 vzero = {0.f, 0.f, 0.f, 0.f};
#pragma unroll
    for (int mi = 0; mi < 4; ++mi)
#pragma unroll
        for (int g = 0; g < 8; ++g) acc[mi][g] = vzero;

    // fragment read byte-offsets within a slot
    int rbA[4], rbB[8];
#pragma unroll
    for (int mi = 0; mi < 4; ++mi) {
        int row = wave * 64 + mi * 16 + l16;
        rbA[mi] = row * 64 + ((lg ^ ((row >> 1) & 3)) << 4);
    }
#pragma unroll
    for (int g = 0; g < 8; ++g) {
        int row = g * 16 + l16;
        rbB[g] = row * 64 + ((lg ^ ((row >> 1) & 3)) << 4);
    }

#define STAGE(KS) do {                                                          \
        const int s_ = (KS) >> 2;                                               \
        const int sl = (KS) % 3;                                                \
        _Pragma("unroll")                                                       \
        for (int it = 0; it < 4; ++it) {                                        \
            unsigned off;                                                       \
            if (s_ == 0)      off = PB_OFF + rowoff[it];                        \
            else if (s_ == 1) off = okT0 ? HB_OFF + rowoff[it] - 8192u : zoff;  \
            else if (s_ == 2) off = HB_OFF + rowoff[it];                        \
            else if (s_ == 3) off = okT1 ? HB_OFF + rowoff[it] + 8192u : zoff;  \
            else if (s_ == 4) off = okN  ? HB_OFF + rowoff[it] - 128u  : zoff;  \
            else              off = GB_OFF + goff[it];                          \
            gload16(ws + off + ((KS) & 3) * 32, smem + sl * 8192 + tid8 + it * 2048); \
        }                                                                       \
        _Pragma("unroll")                                                       \
        for (int it = 0; it < 2; ++it)                                          \
            gload16(ws + offB[it] + (KS) * 32,                                  \
                    smem + 24576 + sl * 4096 + tid8 + it * 2048);               \
    } while (0)

    STAGE(0); STAGE(1);
    asm volatile("s_waitcnt vmcnt(6)" ::: "memory");   // tile 0 landed (1 in flight)
    __builtin_amdgcn_s_barrier();

#pragma unroll
    for (int ks = 0; ks < 24; ++ks) {
        if (ks + 2 < 24) STAGE(ks + 2);
        const char* Ab = (const char*)smem + (ks % 3) * 16384;
        const char* Bb = (const char*)smem + 49152 + (ks % 3) * 8192;
        bf16x8 af[4], bfr[8];
#pragma unroll
        for (int mi = 0; mi < 4; ++mi)
            af[mi] = *(const bf16x8*)(Ab + rbA[mi]);
#pragma unroll
        for (int g = 0; g < 8; ++g)
            bfr[g] = *(const bf16x8*)(Bb + rbB[g]);
#pragma unroll
        for (int g = 0; g < 8; ++g)
#pragma unroll
            for (int mi = 0; mi < 4; ++mi)
                acc[mi][g] = __builtin_amdgcn_mfma_f32_16x16x32_bf16(af[mi], bfr[g], acc[mi][g], 0, 0, 0);
        if (ks < 23) {
            if (ks < 22) asm volatile("s_waitcnt vmcnt(6)" ::: "memory");
            else         asm volatile("s_waitcnt vmcnt(0)" ::: "memory");
            __builtin_amdgcn_s_barrier();
        }
    }
#undef STAGE

    // ---- epilogue: gates + cell update, in-register (8 gates per lane) ----
    const int hcol = ntile * 16 + l16;
    float bv[8];
#pragma unroll
    for (int g = 0; g < 8; ++g) bv[g] = bias[(g * TD + t) * HD + hcol];

#pragma unroll
    for (int mi = 0; mi < 4; ++mi) {
#pragma unroll
        for (int r = 0; r < 4; ++r) {
            int RG = mtile * 256 + wave * 64 + mi * 16 + lg * 4 + r;
            int b  = RG >> 6, nn = RG & 63;
            int bt = b * TD + t;
            int base = ((bt * ND + nn) << 7) + hcol;
            float pre[8];
#pragma unroll
            for (int g = 0; g < 8; ++g) pre[g] = acc[mi][g][r] + bv[g];
            float i_  = sigf(pre[0]);
            float flt = sigf(pre[1]);
            float fft = sigf(pre[2]);
            float frt = sigf(pre[3]);
            float fs  = sigf(pre[4]);
            float gn  = sigf(pre[5]);
            float on  = sigf(pre[6]);
            float cn  = tanhf_fast(pre[7]);
            float ccur = c_h[base];
            float ctb  = (t > 0)      ? c_h[base - ND * HD] : 0.f;
            float cta  = (t < TD - 1) ? c_h[base + ND * HD] : 0.f;
            float csb  = (nn > 0)     ? c_h[base - HD]      : 0.f;
            float cg   = c_g_t[(bt << 7) + hcol];
            float cnew = i_ * cn + flt * ctb + fft * ccur + frt * cta + fs * csb + gn * cg;
            float hnew = on * tanhf_fast(cnew);
            out[OUT_H  + base] = hnew;
            out[OUT_CH + base] = cnew;
        }
    }
}

// ---------------------------------------------------------------------------
// Phase 2 (v2): grid 49 t x 4 bq; block = 4 b's (1 wave each). Stages the six
// 128x128 matrices ONCE per block. hm from staged h_new; f_gtf via MFMA.
// ---------------------------------------------------------------------------
__global__ __launch_bounds__(256, 1) void phase2_kernel(
    const float* __restrict__ g_t, const float* __restrict__ c_g_t,
    const float* __restrict__ Wg,  const float* __restrict__ Zg,
    const float* __restrict__ bg,  float* __restrict__ out)
{
    extern __shared__ char sm2[];
    __bf16* A2  = (__bf16*)sm2;                       // [256][136] h_new bf16
    __bf16* Wb  = (__bf16*)(sm2 + 69632);             // [128][136] staging
    float*  gts = (float*)(sm2 + 69632 + 34816);      // [4][128]
    float*  hm  = (float*)(sm2 + 69632 + 34816 + 2048);
    float*  dts = (float*)(sm2 + 69632 + 34816 + 4096); // [5][4][128]

    int bid = blockIdx.x;
    int t = bid >> 2, bq = bid & 3;
    int tid = threadIdx.x;
    int wv = tid >> 6, lane = tid & 63, lg = lane >> 4, l16 = lane & 15;

    const float* hn  = out + OUT_H;
    const float* chn = out + OUT_CH;

#pragma unroll
    for (int j = 0; j < 32; ++j) {
        int fid = j * 256 + tid;
        int r = fid >> 5, k = (fid & 31) << 2;
        int b = bq * 4 + (r >> 6), nn = r & 63, bt = b * TD + t;
        f32x4 v = *(const f32x4*)(hn + ((bt * ND + nn) << 7) + k);
        bf16x4 w;
        w[0] = (__bf16)v[0]; w[1] = (__bf16)v[1]; w[2] = (__bf16)v[2]; w[3] = (__bf16)v[3];
        *(bf16x4*)(A2 + r * KPAD + k) = w;
    }
#pragma unroll
    for (int j = 0; j < 2; ++j) {
        int idx = j * 256 + tid;
        int b4 = idx >> 7, c = idx & 127;
        gts[idx] = g_t[(((bq * 4 + b4) * TD + t) << 7) + c];
    }
    __syncthreads();

#pragma unroll
    for (int j = 0; j < 2; ++j) {
        int idx = j * 256 + tid;
        int b4 = idx >> 7, c = idx & 127;
        float s = 0.f;
        for (int nn = 0; nn < 64; ++nn) s += (float)A2[(b4 * 64 + nn) * KPAD + c];
        hm[idx] = s * (1.f / 64.f);
    }
    __syncthreads();

    for (int m = 0; m < 5; ++m) {
        const float* M = (m < 3) ? (Zg + ((size_t)(m * TD + t) << 14))
                                 : (Wg + ((size_t)((m - 2) * TD + t) << 14));
#pragma unroll
        for (int j = 0; j < 16; ++j) {
            int fid = j * 256 + tid;
            int k = fid >> 5, c4 = (fid & 31) << 2;
            f32x4 v = *(const f32x4*)(M + (k << 7) + c4);
            bf16x4 w;
            w[0] = (__bf16)v[0]; w[1] = (__bf16)v[1]; w[2] = (__bf16)v[2]; w[3] = (__bf16)v[3];
            *(bf16x4*)(Wb + k * KPAD + c4) = w;
        }
        __syncthreads();
        const float* vec = (m >= 3) ? hm : gts;
#pragma unroll
        for (int j = 0; j < 2; ++j) {
            int idx = j * 256 + tid;
            int b4 = idx >> 7, c = idx & 127;
            float s = 0.f;
            for (int k = 0; k < 128; ++k) s += vec[b4 * 128 + k] * (float)Wb[k * KPAD + c];
            dts[(m * 4 + b4) * 128 + c] = s;
        }
        __syncthreads();
    }

    {
        const float* M = Wg + ((size_t)t << 14);
#pragma unroll
        for (int j = 0; j < 16; ++j) {
            int fid = j * 256 + tid;
            int k = fid >> 5, q = fid & 31;
            f32x4 v = *(const f32x4*)(M + (k << 7) + q * 4);
            int cb = q * 4;
            Wb[(cb + 0) * KPAD + k] = (__bf16)v[0];
            Wb[(cb + 1) * KPAD + k] = (__bf16)v[1];
            Wb[(cb + 2) * KPAD + k] = (__bf16)v[2];
            Wb[(cb + 3) * KPAD + k] = (__bf16)v[3];
        }
        __syncthreads();
    }

    f32x4 acc[4][8];
    const f32x4 vzero = {0.f, 0.f, 0.f, 0.f};
#pragma unroll
    for (int mi = 0; mi < 4; ++mi)
#pragma unroll
        for (int ni = 0; ni < 8; ++ni) acc[mi][ni] = vzero;
#pragma unroll
    for (int ks = 0; ks < 4; ++ks) {
        int kb = ks * 32 + lg * 8;
        bf16x8 a[4];
#pragma unroll
        for (int mi = 0; mi < 4; ++mi)
            a[mi] = *(const bf16x8*)(A2 + (wv * 64 + mi * 16 + l16) * KPAD + kb);
#pragma unroll
        for (int ni = 0; ni < 8; ++ni) {
            bf16x8 bfr = *(const bf16x8*)(Wb + (ni * 16 + l16) * KPAD + kb);
#pragma unroll
            for (int mi = 0; mi < 4; ++mi)
                acc[mi][ni] = __builtin_amdgcn_mfma_f32_16x16x32_bf16(a[mi], bfr, acc[mi][ni], 0, 0, 0);
        }
    }

    int b = bq * 4 + wv, bt = b * TD + t;
#pragma unroll
    for (int ni = 0; ni < 8; ++ni) {
        int col = ni * 16 + l16;
        float z = dts[(0 * 4 + wv) * 128 + col] + bg[t * HD + col];
        float macc = 0.f;
#pragma unroll
        for (int mi = 0; mi < 4; ++mi) {
#pragma unroll
            for (int r = 0; r < 4; ++r) {
                int row = mi * 16 + lg * 4 + r;
                float f  = sigf(acc[mi][ni][r] + z);
                float cv = chn[((bt * ND + row) << 7) + col];
                macc += f * cv;
            }
        }
        macc += __shfl_xor(macc, 16, 64);
        macc += __shfl_xor(macc, 32, 64);
        if (lg == 0) {
            float Mn  = macc * (1.f / 64.f);
            float g_g = sigf(dts[(3 * 4 + wv) * 128 + col] + dts[(1 * 4 + wv) * 128 + col]
                             + bg[(TD + t) * HD + col]);
            float o_g = sigf(dts[(4 * 4 + wv) * 128 + col] + dts[(2 * 4 + wv) * 128 + col]
                             + bg[(2 * TD + t) * HD + col]);
            float cgt = c_g_t[(bt << 7) + col];
            float cgn = Mn + g_g * cgt;
            out[OUT_G  + (bt << 7) + col] = tanhf_fast(cgn) * o_g;
            out[OUT_CG + (bt << 7) + col] = cgn;
        }
    }
}

extern "C" void kernel_launch(void* const* d_in, const int* in_sizes, int n_in,
                              void* d_out, int out_size, void* d_ws, size_t ws_size,
                              hipStream_t stream) {
    const float* h     = (const float*)d_in[0];
    const float* c_h   = (const float*)d_in[1];
    const float* p     = (const float*)d_in[2];
    const float* g_t   = (const float*)d_in[3];
    const float* c_g_t = (const float*)d_in[4];
    const float* U     = (const float*)d_in[5];
    const float* Wt    = (const float*)d_in[6];
    const float* Ws    = (const float*)d_in[7];
    const float* Zt    = (const float*)d_in[8];
    const float* b     = (const float*)d_in[9];
    const float* Wg    = (const float*)d_in[10];
    const float* Zg    = (const float*)d_in[11];
    const float* bg    = (const float*)d_in[12];
    float* out = (float*)d_out;
    __bf16* ws = (__bf16*)d_ws;

    prep_acts<<<12644, 256, 0, stream>>>(h, p, g_t, ws);
    prep_w<<<TD * 8 * 12, 256, 0, stream>>>(U, Wt, Ws, Zt, ws + WP_OFF);

    (void)hipFuncSetAttribute(reinterpret_cast<const void*>(phase1_kernel),
                              hipFuncAttributeMaxDynamicSharedMemorySize, LDS1_BYTES);
    (void)hipFuncSetAttribute(reinterpret_cast<const void*>(phase2_kernel),
                              hipFuncAttributeMaxDynamicSharedMemorySize, LDS2_BYTES);
    phase1_kernel<<<TD * 32, 256, LDS1_BYTES, stream>>>(ws, c_h, c_g_t, b, out);
    phase2_kernel<<<TD * 4, 256, LDS2_BYTES, stream>>>(g_t, c_g_t, Wg, Zg, bg, out);
}

// Round 9
// 282.160 us; speedup vs baseline: 1.0010x; 1.0010x over previous
//
#include <hip/hip_runtime.h>
#include <hip/hip_bf16.h>

#define TD 49
#define BD 16
#define ND 64
#define HD 128

typedef float  f32x4  __attribute__((ext_vector_type(4)));
typedef __bf16 bf16x8 __attribute__((ext_vector_type(8)));
typedef __bf16 bf16x4 __attribute__((ext_vector_type(4)));

// ---------------- workspace layout (bf16 element offsets) ----------------
// W' [t][g][h=128][k=640], k-order = [U | Wt0 | Wt1 | Wt2 | Ws]
#define WP_OFF   0u
#define HB_OFF   32112640u           // h  bf16 [B,T,N,H]
#define ACT_ELEMS 6422528u
#define PB_OFF   38535168u           // p  bf16
#define GB_OFF   44957696u           // g_t bf16 [B,T,H] (kept, cheap)
#define GT_ELEMS 100352u
#define ZP_OFF   45058048u           // 2048 bf16 zeros (pad source page)
#define ZB_OFF   45060096u           // f32 zb[b,t,g,h] = Zt.g_t + b  (802816 f32)
// total = 46,665,728 bf16 elems = 93.3 MB

#define OUT_H    0
#define OUT_CH   6422528
#define OUT_G    12845056
#define OUT_CG   12945408

#define KPAD 136
#define LDS1_BYTES 65536             // 4 slots x (A 8KB + B 8KB) -> 2 blocks/CU
#define LDS2_BYTES 118784

#define NB_ACTS 12644
#define NB_W    3920                 // 49*8*10
#define NB_ZB   392                  // 49*8

__device__ __forceinline__ float sigf(float x) {
    return 1.0f / (1.0f + exp2f(-1.442695041f * x));
}
__device__ __forceinline__ float tanhf_fast(float x) {
    x = fminf(fmaxf(x, -20.f), 20.f);
    float e = exp2f(2.885390082f * x);
    return (e - 1.f) / (e + 1.f);
}
__device__ __forceinline__ void gload16(const void* g, void* l) {
    __builtin_amdgcn_global_load_lds((const __attribute__((address_space(1))) void*)g,
                                     (__attribute__((address_space(3))) void*)l, 16, 0, 0);
}

// ---------------------------------------------------------------------------
// prep (fused): [0,NB_ACTS) cast h/p/g_t -> bf16 + zero page;
//               [.., +NB_W) transpose+cast weights to W' (k=640);
//               [.., +NB_ZB) zb[b,t,g,h] = sum_k g_t*Zt + bias  (f32 exact).
// ---------------------------------------------------------------------------
__global__ __launch_bounds__(256) void prep_kernel(
    const float* __restrict__ h,  const float* __restrict__ p,
    const float* __restrict__ g,  const float* __restrict__ U,
    const float* __restrict__ Wt, const float* __restrict__ Ws,
    const float* __restrict__ Zt, const float* __restrict__ bias,
    __bf16* __restrict__ ws)
{
    __shared__ __bf16 tile[64 * 132];
    const int bid = blockIdx.x;
    const int tid = threadIdx.x;

    if (bid < NB_ACTS) {
        unsigned i = bid * 256u + tid;
        const unsigned HU = ACT_ELEMS / 4u, GU = GT_ELEMS / 4u;
        const float* src;
        unsigned dst;
        if (i < HU)              { src = h + (size_t)i * 4;            dst = HB_OFF + i * 4; }
        else if (i < 2u*HU)      { unsigned j = i - HU;    src = p + (size_t)j * 4; dst = PB_OFF + j * 4; }
        else if (i < 2u*HU + GU) { unsigned j = i - 2u*HU; src = g + (size_t)j * 4; dst = GB_OFF + j * 4; }
        else if (i < 2u*HU + GU + 512u) {
            unsigned j = i - 2u*HU - GU;
            bf16x4 z = {};
            *(bf16x4*)(ws + ZP_OFF + j * 4) = z;
            return;
        } else return;
        f32x4 v = *(const f32x4*)src;
        bf16x4 w;
        w[0] = (__bf16)v[0]; w[1] = (__bf16)v[1]; w[2] = (__bf16)v[2]; w[3] = (__bf16)v[3];
        *(bf16x4*)(ws + dst) = w;
        return;
    }

    if (bid < NB_ACTS + NB_W) {
        int wb = bid - NB_ACTS;
        int tg = wb / 10, c = wb % 10;
        int t  = tg >> 3, gg = tg & 7;
        int gt = gg * TD + t;
        int k0 = c * 64;
#pragma unroll
        for (int u = 0; u < 8; ++u) {
            int unit = u * 256 + tid;
            int kk = unit >> 5;
            int h4 = (unit & 31) << 2;
            int k  = k0 + kk;
            const float* src;
            if (k < 128)      src = U  + ((size_t)(gt * 128 + k)       << 7);
            else if (k < 512) src = Wt + ((size_t)(gt * 384 + (k-128)) << 7);
            else              src = Ws + ((size_t)(gt * 128 + (k-512)) << 7);
            f32x4 v = *(const f32x4*)(src + h4);
            bf16x4 w;
            w[0] = (__bf16)v[0]; w[1] = (__bf16)v[1]; w[2] = (__bf16)v[2]; w[3] = (__bf16)v[3];
            *(bf16x4*)(tile + kk * 132 + h4) = w;
        }
        __syncthreads();
#pragma unroll
        for (int u = 0; u < 2; ++u) {
            int unit = u * 256 + tid;
            int hh = unit >> 2;
            int kg = unit & 3;
            bf16x8 v0, v1;
#pragma unroll
            for (int j = 0; j < 8; ++j) v0[j] = tile[(kg * 16 + j) * 132 + hh];
#pragma unroll
            for (int j = 0; j < 8; ++j) v1[j] = tile[(kg * 16 + 8 + j) * 132 + hh];
            __bf16* dst = ws + WP_OFF + (size_t)(tg * 128 + hh) * 640 + k0 + kg * 16;
            *(bf16x8*)dst       = v0;
            *(bf16x8*)(dst + 8) = v1;
        }
        return;
    }

    // ---- zb: block = (t, gate)
    {
        int zid = bid - NB_ACTS - NB_W;
        int t = zid >> 3, gg = zid & 7;
        int h_ = tid & 127, bh = tid >> 7;          // 2 halves x 8 batches
        float* zbf = (float*)(ws + ZB_OFF);
        float s[8];
        float bv = bias[(gg * TD + t) * HD + h_];
#pragma unroll
        for (int b8 = 0; b8 < 8; ++b8) s[b8] = bv;
        const float* Zrow = Zt + ((size_t)(gg * TD + t) << 14) + h_;
        for (int k = 0; k < 128; ++k) {
            float zv = Zrow[k << 7];
#pragma unroll
            for (int b8 = 0; b8 < 8; ++b8)
                s[b8] += g[(((bh * 8 + b8) * TD + t) << 7) + k] * zv;
        }
#pragma unroll
        for (int b8 = 0; b8 < 8; ++b8) {
            int bt = (bh * 8 + b8) * TD + t;
            zbf[(bt * 8 + gg) * HD + h_] = s[b8];
        }
    }
}

// ---------------------------------------------------------------------------
// Phase 1: 128x128 tile (M=128, N = 8 gates x 16 hcols), BK=32, K=640
// (20 steps), 4 LDS slots, depth-3 prefetch, counted vmcnt(8) + raw barrier.
// 4 waves, wave = 32 rows x all 8 gates (in-register gate epilogue, bias=zb).
// Slot math: step ks stages tile ks+3 into slot (ks+3)&3 = (ks-1)&3 (freed by
// end-of-step-(ks-1) barrier); vmcnt(8) at step end => tile ks+1 landed.
// ---------------------------------------------------------------------------
__global__ __launch_bounds__(256, 2) void phase1_kernel(
    const __bf16* __restrict__ ws,
    const float* __restrict__ c_h, const float* __restrict__ c_g_t,
    float* __restrict__ out)
{
    extern __shared__ __bf16 smem[];     // A slots elems [0,16384); B: [16384,32768)
    const __bf16* hb = ws + HB_OFF;
    const __bf16* pb = ws + PB_OFF;
    const __bf16* wp = ws + WP_OFF;
    const __bf16* zp = ws + ZP_OFF;
    const float*  zb = (const float*)(ws + ZB_OFF);

    int bid = blockIdx.x;
    int swz = (bid & 7) * 392 + (bid >> 3);  // bijective, 3136 = 8*392
    int t     = swz >> 6;
    int rem   = swz & 63;
    int mtile = rem >> 3, ntile = rem & 7;

    int tid  = threadIdx.x;
    int wave = tid >> 6, lane = tid & 63;
    int lg = lane >> 4, l16 = lane & 15;

    // ---- staging maps: chunk = it*256+tid covers 16B of a slot
    const __bf16* pA[2][5];
    const __bf16* pB[2];
    int dstA[2], dstB[2];
#pragma unroll
    for (int it = 0; it < 2; ++it) {
        int chunk = it * 256 + tid;          // [0,512)
        int row   = chunk >> 2;              // [0,128)
        int k16   = chunk & 3;
        int ke    = (k16 ^ ((row >> 1) & 3)) * 8;   // swizzled k elem offset
        int b_ = mtile * 2 + (row >> 6), n_ = row & 63, bt_ = b_ * TD + t;
        pA[it][0] = pb + ((bt_ * ND + n_) << 7) + ke;
        pA[it][1] = (t > 0)      ? hb + (((bt_ - 1) * ND + n_) << 7) + ke : zp + ke;
        pA[it][2] = hb + ((bt_ * ND + n_) << 7) + ke;
        pA[it][3] = (t < TD - 1) ? hb + (((bt_ + 1) * ND + n_) << 7) + ke : zp + ke;
        pA[it][4] = (n_ > 0)     ? hb + ((bt_ * ND + n_ - 1) << 7) + ke : zp + ke;
        int g_ = row >> 4, hc = row & 15;
        pB[it] = wp + (size_t)((t * 8 + g_) * 128 + ntile * 16 + hc) * 640 + ke;
        dstA[it] = chunk * 8;
        dstB[it] = 16384 + chunk * 8;
    }

    // ---- fragment read byte-offsets (A within slot; B folded +32768 bytes)
    int rbA[2], rbB[8];
#pragma unroll
    for (int mi = 0; mi < 2; ++mi) {
        int row = wave * 32 + mi * 16 + l16;
        rbA[mi] = row * 64 + ((lg ^ ((row >> 1) & 3)) << 4);
    }
#pragma unroll
    for (int g = 0; g < 8; ++g) {
        int row = g * 16 + l16;
        rbB[g] = 32768 + row * 64 + ((lg ^ ((row >> 1) & 3)) << 4);
    }

    f32x4 acc[2][8];
    const f32x4 vzero = {0.f, 0.f, 0.f, 0.f};
#pragma unroll
    for (int mi = 0; mi < 2; ++mi)
#pragma unroll
        for (int g = 0; g < 8; ++g) acc[mi][g] = vzero;

#define STAGE(KS) do {                                                          \
        _Pragma("unroll")                                                       \
        for (int it = 0; it < 2; ++it) {                                        \
            gload16(pA[it][(KS) >> 2] + ((KS) & 3) * 32,                        \
                    smem + ((KS) & 3) * 4096 + dstA[it]);                       \
            gload16(pB[it] + (KS) * 32,                                         \
                    smem + ((KS) & 3) * 4096 + dstB[it]);                       \
        }                                                                       \
    } while (0)

    STAGE(0); STAGE(1); STAGE(2);
    asm volatile("s_waitcnt vmcnt(8)" ::: "memory");   // tile 0 landed (1,2 in flight)
    __builtin_amdgcn_s_barrier();

#pragma unroll
    for (int ks = 0; ks < 20; ++ks) {
        if (ks + 3 < 20) STAGE(ks + 3);
        const char* base = (const char*)smem + (ks & 3) * 8192;
        bf16x8 af[2], bfr[8];
        af[0] = *(const bf16x8*)(base + rbA[0]);
        af[1] = *(const bf16x8*)(base + rbA[1]);
#pragma unroll
        for (int g = 0; g < 8; ++g)
            bfr[g] = *(const bf16x8*)(base + rbB[g]);
#pragma unroll
        for (int g = 0; g < 8; ++g) {
            acc[0][g] = __builtin_amdgcn_mfma_f32_16x16x32_bf16(af[0], bfr[g], acc[0][g], 0, 0, 0);
            acc[1][g] = __builtin_amdgcn_mfma_f32_16x16x32_bf16(af[1], bfr[g], acc[1][g], 0, 0, 0);
        }
        if (ks < 19) {
            if (ks < 17)       asm volatile("s_waitcnt vmcnt(8)" ::: "memory");
            else if (ks == 17) asm volatile("s_waitcnt vmcnt(4)" ::: "memory");
            else               asm volatile("s_waitcnt vmcnt(0)" ::: "memory");
            __builtin_amdgcn_s_barrier();
        }
    }
#undef STAGE

    // ---- epilogue: gates + cell update; bias comes from precomputed zb ----
    const int hcol = ntile * 16 + l16;
#pragma unroll
    for (int mi = 0; mi < 2; ++mi) {
#pragma unroll
        for (int r = 0; r < 4; ++r) {
            int RG = mtile * 128 + wave * 32 + mi * 16 + lg * 4 + r;
            int b  = RG >> 6, nn = RG & 63;
            int bt = b * TD + t;
            int base = ((bt * ND + nn) << 7) + hcol;
            const float* zrow = zb + (bt * 8) * HD + hcol;
            float pre[8];
#pragma unroll
            for (int g = 0; g < 8; ++g) pre[g] = acc[mi][g][r] + zrow[g * HD];
            float i_  = sigf(pre[0]);
            float flt = sigf(pre[1]);
            float fft = sigf(pre[2]);
            float frt = sigf(pre[3]);
            float fs  = sigf(pre[4]);
            float gn  = sigf(pre[5]);
            float on  = sigf(pre[6]);
            float cn  = tanhf_fast(pre[7]);
            float ccur = c_h[base];
            float ctb  = (t > 0)      ? c_h[base - ND * HD] : 0.f;
            float cta  = (t < TD - 1) ? c_h[base + ND * HD] : 0.f;
            float csb  = (nn > 0)     ? c_h[base - HD]      : 0.f;
            float cg   = c_g_t[(bt << 7) + hcol];
            float cnew = i_ * cn + flt * ctb + fft * ccur + frt * cta + fs * csb + gn * cg;
            float hnew = on * tanhf_fast(cnew);
            out[OUT_H  + base] = hnew;
            out[OUT_CH + base] = cnew;
        }
    }
}

// ---------------------------------------------------------------------------
// Phase 2: grid 49 t x 4 bq; block = 4 b's (1 wave each). Stages the six
// 128x128 matrices ONCE per block. hm from staged h_new; f_gtf via MFMA.
// ---------------------------------------------------------------------------
__global__ __launch_bounds__(256, 1) void phase2_kernel(
    const float* __restrict__ g_t, const float* __restrict__ c_g_t,
    const float* __restrict__ Wg,  const float* __restrict__ Zg,
    const float* __restrict__ bg,  float* __restrict__ out)
{
    extern __shared__ char sm2[];
    __bf16* A2  = (__bf16*)sm2;                       // [256][136] h_new bf16
    __bf16* Wb  = (__bf16*)(sm2 + 69632);             // [128][136] staging
    float*  gts = (float*)(sm2 + 69632 + 34816);      // [4][128]
    float*  hm  = (float*)(sm2 + 69632 + 34816 + 2048);
    float*  dts = (float*)(sm2 + 69632 + 34816 + 4096); // [5][4][128]

    int bid = blockIdx.x;
    int t = bid >> 2, bq = bid & 3;
    int tid = threadIdx.x;
    int wv = tid >> 6, lane = tid & 63, lg = lane >> 4, l16 = lane & 15;

    const float* hn  = out + OUT_H;
    const float* chn = out + OUT_CH;

#pragma unroll
    for (int j = 0; j < 32; ++j) {
        int fid = j * 256 + tid;
        int r = fid >> 5, k = (fid & 31) << 2;
        int b = bq * 4 + (r >> 6), nn = r & 63, bt = b * TD + t;
        f32x4 v = *(const f32x4*)(hn + ((bt * ND + nn) << 7) + k);
        bf16x4 w;
        w[0] = (__bf16)v[0]; w[1] = (__bf16)v[1]; w[2] = (__bf16)v[2]; w[3] = (__bf16)v[3];
        *(bf16x4*)(A2 + r * KPAD + k) = w;
    }
#pragma unroll
    for (int j = 0; j < 2; ++j) {
        int idx = j * 256 + tid;
        int b4 = idx >> 7, c = idx & 127;
        gts[idx] = g_t[(((bq * 4 + b4) * TD + t) << 7) + c];
    }
    __syncthreads();

#pragma unroll
    for (int j = 0; j < 2; ++j) {
        int idx = j * 256 + tid;
        int b4 = idx >> 7, c = idx & 127;
        float s = 0.f;
        for (int nn = 0; nn < 64; ++nn) s += (float)A2[(b4 * 64 + nn) * KPAD + c];
        hm[idx] = s * (1.f / 64.f);
    }
    __syncthreads();

    for (int m = 0; m < 5; ++m) {
        const float* M = (m < 3) ? (Zg + ((size_t)(m * TD + t) << 14))
                                 : (Wg + ((size_t)((m - 2) * TD + t) << 14));
#pragma unroll
        for (int j = 0; j < 16; ++j) {
            int fid = j * 256 + tid;
            int k = fid >> 5, c4 = (fid & 31) << 2;
            f32x4 v = *(const f32x4*)(M + (k << 7) + c4);
            bf16x4 w;
            w[0] = (__bf16)v[0]; w[1] = (__bf16)v[1]; w[2] = (__bf16)v[2]; w[3] = (__bf16)v[3];
            *(bf16x4*)(Wb + k * KPAD + c4) = w;
        }
        __syncthreads();
        const float* vec = (m >= 3) ? hm : gts;
#pragma unroll
        for (int j = 0; j < 2; ++j) {
            int idx = j * 256 + tid;
            int b4 = idx >> 7, c = idx & 127;
            float s = 0.f;
            for (int k = 0; k < 128; ++k) s += vec[b4 * 128 + k] * (float)Wb[k * KPAD + c];
            dts[(m * 4 + b4) * 128 + c] = s;
        }
        __syncthreads();
    }

    {
        const float* M = Wg + ((size_t)t << 14);
#pragma unroll
        for (int j = 0; j < 16; ++j) {
            int fid = j * 256 + tid;
            int k = fid >> 5, q = fid & 31;
            f32x4 v = *(const f32x4*)(M + (k << 7) + q * 4);
            int cb = q * 4;
            Wb[(cb + 0) * KPAD + k] = (__bf16)v[0];
            Wb[(cb + 1) * KPAD + k] = (__bf16)v[1];
            Wb[(cb + 2) * KPAD + k] = (__bf16)v[2];
            Wb[(cb + 3) * KPAD + k] = (__bf16)v[3];
        }
        __syncthreads();
    }

    f32x4 acc[4][8];
    const f32x4 vzero = {0.f, 0.f, 0.f, 0.f};
#pragma unroll
    for (int mi = 0; mi < 4; ++mi)
#pragma unroll
        for (int ni = 0; ni < 8; ++ni) acc[mi][ni] = vzero;
#pragma unroll
    for (int ks = 0; ks < 4; ++ks) {
        int kb = ks * 32 + lg * 8;
        bf16x8 a[4];
#pragma unroll
        for (int mi = 0; mi < 4; ++mi)
            a[mi] = *(const bf16x8*)(A2 + (wv * 64 + mi * 16 + l16) * KPAD + kb);
#pragma unroll
        for (int ni = 0; ni < 8; ++ni) {
            bf16x8 bfr = *(const bf16x8*)(Wb + (ni * 16 + l16) * KPAD + kb);
#pragma unroll
            for (int mi = 0; mi < 4; ++mi)
                acc[mi][ni] = __builtin_amdgcn_mfma_f32_16x16x32_bf16(a[mi], bfr, acc[mi][ni], 0, 0, 0);
        }
    }

    int b = bq * 4 + wv, bt = b * TD + t;
#pragma unroll
    for (int ni = 0; ni < 8; ++ni) {
        int col = ni * 16 + l16;
        float z = dts[(0 * 4 + wv) * 128 + col] + bg[t * HD + col];
        float macc = 0.f;
#pragma unroll
        for (int mi = 0; mi < 4; ++mi) {
#pragma unroll
            for (int r = 0; r < 4; ++r) {
                int row = mi * 16 + lg * 4 + r;
                float f  = sigf(acc[mi][ni][r] + z);
                float cv = chn[((bt * ND + row) << 7) + col];
                macc += f * cv;
            }
        }
        macc += __shfl_xor(macc, 16, 64);
        macc += __shfl_xor(macc, 32, 64);
        if (lg == 0) {
            float Mn  = macc * (1.f / 64.f);
            float g_g = sigf(dts[(3 * 4 + wv) * 128 + col] + dts[(1 * 4 + wv) * 128 + col]
                             + bg[(TD + t) * HD + col]);
            float o_g = sigf(dts[(4 * 4 + wv) * 128 + col] + dts[(2 * 4 + wv) * 128 + col]
                             + bg[(2 * TD + t) * HD + col]);
            float cgt = c_g_t[(bt << 7) + col];
            float cgn = Mn + g_g * cgt;
            out[OUT_G  + (bt << 7) + col] = tanhf_fast(cgn) * o_g;
            out[OUT_CG + (bt << 7) + col] = cgn;
        }
    }
}

extern "C" void kernel_launch(void* const* d_in, const int* in_sizes, int n_in,
                              void* d_out, int out_size, void* d_ws, size_t ws_size,
                              hipStream_t stream) {
    const float* h     = (const float*)d_in[0];
    const float* c_h   = (const float*)d_in[1];
    const float* p     = (const float*)d_in[2];
    const float* g_t   = (const float*)d_in[3];
    const float* c_g_t = (const float*)d_in[4];
    const float* U     = (const float*)d_in[5];
    const float* Wt    = (const float*)d_in[6];
    const float* Ws    = (const float*)d_in[7];
    const float* Zt    = (const float*)d_in[8];
    const float* b     = (const float*)d_in[9];
    const float* Wg    = (const float*)d_in[10];
    const float* Zg    = (const float*)d_in[11];
    const float* bg    = (const float*)d_in[12];
    float* out = (float*)d_out;
    __bf16* ws = (__bf16*)d_ws;

    prep_kernel<<<NB_ACTS + NB_W + NB_ZB, 256, 0, stream>>>(h, p, g_t, U, Wt, Ws, Zt, b, ws);

    (void)hipFuncSetAttribute(reinterpret_cast<const void*>(phase1_kernel),
                              hipFuncAttributeMaxDynamicSharedMemorySize, LDS1_BYTES);
    (void)hipFuncSetAttribute(reinterpret_cast<const void*>(phase2_kernel),
                              hipFuncAttributeMaxDynamicSharedMemorySize, LDS2_BYTES);
    phase1_kernel<<<TD * 64, 256, LDS1_BYTES, stream>>>(ws, c_h, c_g_t, out);
    phase2_kernel<<<TD * 4, 256, LDS2_BYTES, stream>>>(g_t, c_g_t, Wg, Zg, bg, out);
}